// Round 13
// baseline (240.147 us; speedup 1.0000x reference)
//
#include <hip/hip_runtime.h>

using bf16x8 = __attribute__((ext_vector_type(8))) __bf16;
using f32x4  = __attribute__((ext_vector_type(4))) float;

__device__ __forceinline__ f32x4 mfma16(bf16x8 a, bf16x8 b, f32x4 c) {
  return __builtin_amdgcn_mfma_f32_16x16x32_bf16(a, b, c, 0, 0, 0);
}

__device__ __forceinline__ unsigned short f2bf(float f) {
  union { float f; unsigned int u; } x; x.f = f;
  unsigned int u = x.u + 0x7FFFu + ((x.u >> 16) & 1u);
  return (unsigned short)(u >> 16);
}

__device__ __forceinline__ unsigned int cvtpk_bf16(float lo, float hi) {
  unsigned int r;
  asm("v_cvt_pk_bf16_f32 %0, %1, %2" : "=v"(r) : "v"(lo), "v"(hi));
  return r;
}

// raw v_exp_f32: inputs bounded (|S*KSCL| < ~1.3) so no libm range fixup needed
__device__ __forceinline__ float fexp2(float x) {
#if __has_builtin(__builtin_amdgcn_exp2f)
  return __builtin_amdgcn_exp2f(x);
#else
  float r; asm("v_exp_f32 %0, %1" : "=v"(r) : "v"(x)); return r;
#endif
}

__device__ __forceinline__ void gl_lds16(const unsigned short* g, unsigned short* l) {
  __builtin_amdgcn_global_load_lds(
      (__attribute__((address_space(1))) void*)(g),
      (__attribute__((address_space(3))) void*)(l), 16, 0, 0);
}

// swizzled read from a 64-elem-row LDS tile staged with chunk ^= (row&7)
__device__ __forceinline__ bf16x8 rdsw64(const unsigned short* base, int r, int ch) {
  int c = ch ^ (r & 7);
  return *reinterpret_cast<const bf16x8*>(base + ((size_t)r * 8 + c) * 8);
}

// ---------- transpose + f32->bf16: out[b][c][r] = in[b][r][c] ----------
__global__ __launch_bounds__(256) void transpose_cvt(const float* __restrict__ in,
                                                     unsigned short* __restrict__ out,
                                                     int R, int C) {
  __shared__ float t[32][33];
  int b = blockIdx.z;
  const float* inb = in + (size_t)b * R * C;
  unsigned short* outb = out + (size_t)b * R * C;
  int tx = threadIdx.x & 31, ty = threadIdx.x >> 5;
  int c0 = blockIdx.x * 32, r0 = blockIdx.y * 32;
#pragma unroll
  for (int i = 0; i < 4; ++i)
    t[ty + i * 8][tx] = inb[(size_t)(r0 + ty + i * 8) * C + c0 + tx];
  __syncthreads();
#pragma unroll
  for (int i = 0; i < 4; ++i)
    outb[(size_t)(c0 + ty + i * 8) * R + r0 + tx] = f2bf(t[tx][ty + i * 8]);
}

// ---------- layernorm (rows of 1024) f32 -> bf16 ----------
__global__ __launch_bounds__(256) void ln_bf16(const float* __restrict__ x,
                                               const float* __restrict__ g,
                                               const float* __restrict__ bta,
                                               unsigned short* __restrict__ out) {
  int row = blockIdx.x, tid = threadIdx.x;
  float4 v = reinterpret_cast<const float4*>(x + (size_t)row * 1024)[tid];
  float s = v.x + v.y + v.z + v.w;
  float s2 = v.x * v.x + v.y * v.y + v.z * v.z + v.w * v.w;
#pragma unroll
  for (int m = 1; m < 64; m <<= 1) { s += __shfl_xor(s, m); s2 += __shfl_xor(s2, m); }
  __shared__ float red[8];
  int w = tid >> 6;
  if ((tid & 63) == 0) { red[w] = s; red[w + 4] = s2; }
  __syncthreads();
  s  = red[0] + red[1] + red[2] + red[3];
  s2 = red[4] + red[5] + red[6] + red[7];
  float mean = s * (1.f / 1024.f);
  float var  = s2 * (1.f / 1024.f) - mean * mean;
  float rstd = rsqrtf(var + 1e-5f);
  float4 gv = reinterpret_cast<const float4*>(g)[tid];
  float4 bv = reinterpret_cast<const float4*>(bta)[tid];
  ushort4 o;
  o.x = f2bf((v.x - mean) * rstd * gv.x + bv.x);
  o.y = f2bf((v.y - mean) * rstd * gv.y + bv.y);
  o.z = f2bf((v.z - mean) * rstd * gv.z + bv.z);
  o.w = f2bf((v.w - mean) * rstd * gv.w + bv.w);
  reinterpret_cast<ushort4*>(out + (size_t)row * 1024)[tid] = o;
}

// ================= 256x256 8-phase GEMM (MLP1): C=relu(A*Bt^T+bias), bf16 out =====
__device__ __forceinline__ void stage_half(const unsigned short* gbase, int K,
                                           unsigned short* lds, int tid) {
#pragma unroll
  for (int j = 0; j < 2; ++j) {
    int lr = j * 64 + (tid >> 3);
    int c  = (tid & 7) ^ (lr & 7);
    gl_lds16(gbase + (size_t)lr * K + c * 8, lds + (size_t)(j * 512 + tid) * 8);
  }
}

__device__ __forceinline__ bf16x8 rdfrag(const unsigned short* base, int r, int k) {
  return *reinterpret_cast<const bf16x8*>(base + ((size_t)r * 8 + (k ^ (r & 7))) * 8);
}

__global__ __launch_bounds__(512, 2) void gemm256_relu(const unsigned short* __restrict__ A,
                                                       const unsigned short* __restrict__ Bt,
                                                       unsigned short* __restrict__ C,
                                                       const float* __restrict__ bias,
                                                       int M, int N, int K) {
  __shared__ __align__(16) unsigned short LA[2][256 * 64];
  __shared__ __align__(16) unsigned short LB[2][256 * 64];
  int tid = threadIdx.x, lane = tid & 63, w = tid >> 6;
  int l15 = lane & 15, lh = lane >> 4;
  int wr = (w >> 2) * 128, wc = (w & 3) * 64;
  int bid = blockIdx.x;
  int xcd = bid & 7, g = bid >> 3;
  int bm = (xcd >> 1) * 4 + (g >> 3);
  int bn = (xcd & 1) * 8 + (g & 7);
  const unsigned short* Ab = A + (size_t)(bm * 256) * K;
  const unsigned short* Bb = Bt + (size_t)(bn * 256) * K;
  f32x4 acc[8][4] = {};
  int NT = K >> 6;
  stage_half(Ab, K, &LA[0][0], tid);
  stage_half(Ab + (size_t)128 * K, K, &LA[0][128 * 64], tid);
  stage_half(Bb, K, &LB[0][0], tid);
  stage_half(Bb + (size_t)128 * K, K, &LB[0][128 * 64], tid);
  asm volatile("s_waitcnt vmcnt(0)" ::: "memory");
  __builtin_amdgcn_s_barrier();
  for (int t = 0; t < NT; ++t) {
    int cur = t & 1;
    const unsigned short* la = &LA[cur][0];
    const unsigned short* lb = &LB[cur][0];
    unsigned short* na = &LA[cur ^ 1][0];
    unsigned short* nb = &LB[cur ^ 1][0];
    int k0n = (t + 1) << 6;
    bool more = (t + 1 < NT);
    bf16x8 bfr[4][2];
#pragma unroll
    for (int q = 0; q < 4; ++q) {
      if (more) {
        if (q == 0)      stage_half(Ab + k0n, K, na, tid);
        else if (q == 1) stage_half(Ab + (size_t)128 * K + k0n, K, na + 128 * 64, tid);
        else if (q == 2) stage_half(Bb + k0n, K, nb, tid);
        else             stage_half(Bb + (size_t)128 * K + k0n, K, nb + 128 * 64, tid);
      }
      if (q == 0) {
        if (more) asm volatile("s_waitcnt vmcnt(2)" ::: "memory");
        else      asm volatile("s_waitcnt vmcnt(0)" ::: "memory");
        __builtin_amdgcn_s_barrier();
      }
      bf16x8 aq[2][2];
#pragma unroll
      for (int i = 0; i < 2; ++i)
#pragma unroll
        for (int kk = 0; kk < 2; ++kk)
          aq[i][kk] = rdfrag(la, wr + q * 32 + i * 16 + l15, kk * 4 + lh);
      if (q == 0) {
#pragma unroll
        for (int ni = 0; ni < 4; ++ni)
#pragma unroll
          for (int kk = 0; kk < 2; ++kk)
            bfr[ni][kk] = rdfrag(lb, wc + ni * 16 + l15, kk * 4 + lh);
      }
      if (q != 0) __builtin_amdgcn_s_barrier();
      __builtin_amdgcn_s_setprio(1);
#pragma unroll
      for (int kk = 0; kk < 2; ++kk)
#pragma unroll
        for (int i = 0; i < 2; ++i)
#pragma unroll
          for (int ni = 0; ni < 4; ++ni)
            acc[q * 2 + i][ni] = mfma16(aq[i][kk], bfr[ni][kk], acc[q * 2 + i][ni]);
      __builtin_amdgcn_s_setprio(0);
      __builtin_amdgcn_s_barrier();
    }
  }
#pragma unroll
  for (int mi = 0; mi < 8; ++mi)
#pragma unroll
    for (int ni = 0; ni < 4; ++ni) {
      int row0 = bm * 256 + wr + mi * 16 + lh * 4;
      int col  = bn * 256 + wc + ni * 16 + l15;
      float bv = bias[col];
#pragma unroll
      for (int r = 0; r < 4; ++r) {
        float v = fmaxf(acc[mi][ni][r] + bv, 0.f);
        C[(size_t)(row0 + r) * N + col] = f2bf(v);
      }
    }
}

// ---------- bf16 MFMA GEMM: C[M][N] = A[M][K] * Bt[N][K]^T ----------
// BK=128, T2 both-sides swizzle (chunk ^= (row&7)<<1), TM x 128 tile, 4 waves.
#define GBK 128
#define KSCL 0.04508422f  /* (1/32) * log2(e): S*KSCL feeds exp2 */

__device__ __forceinline__ bf16x8 rd128(const unsigned short* base, int r, int ch) {
  int c = ch ^ ((r & 7) << 1);
  return *reinterpret_cast<const bf16x8*>(base + (size_t)r * GBK + c * 8);
}

template<int TM, int MODE>
__global__ __launch_bounds__(256) void gemm_bf16(const unsigned short* __restrict__ A,
                                                 const unsigned short* __restrict__ Bt,
                                                 void* __restrict__ Cout,
                                                 unsigned short* __restrict__ Cout2,
                                                 const float* __restrict__ bias,
                                                 const float* __restrict__ resid,
                                                 const float* __restrict__ scvec,
                                                 int M, int N, int K) {
  constexpr int MI = TM / 32;
  constexpr int AJ = TM / 16;
  __shared__ __align__(16) unsigned short Sh[(TM + 128) * GBK];
  unsigned short* As = Sh;
  unsigned short* Bs = Sh + TM * GBK;
  int tid = threadIdx.x;
  int lane = tid & 63, w = tid >> 6;
  int l15 = lane & 15, lh = lane >> 4;
  int wr = (w >> 1) * (TM / 2), wc = (w & 1) * 64;
  int nblk = N >> 7;
  int rows = M / TM;
  int bm, bn;
  if (nblk == 8 && (rows & 7) == 0) {
    int bid = blockIdx.x;
    int xcd = bid & 7, g = bid >> 3;
    bm = xcd * (rows >> 3) + (g >> 3);
    bn = g & 7;
  } else {
    bm = blockIdx.x / nblk; bn = blockIdx.x % nblk;
  }
  const unsigned short* ApJ[AJ];
  const unsigned short* BpJ[8];
#pragma unroll
  for (int j = 0; j < AJ; ++j) {
    int row = j * 16 + (tid >> 4);
    int ch  = (tid & 15) ^ ((row & 7) << 1);
    ApJ[j] = A + (size_t)(bm * TM + row) * K + ch * 8;
  }
#pragma unroll
  for (int j = 0; j < 8; ++j) {
    int row = j * 16 + (tid >> 4);
    int ch  = (tid & 15) ^ ((row & 7) << 1);
    BpJ[j] = Bt + (size_t)(bn * 128 + row) * K + ch * 8;
  }
  f32x4 acc[MI][4] = {};
  for (int k0 = 0; k0 < K; k0 += GBK) {
#pragma unroll
    for (int j = 0; j < AJ; ++j)
      gl_lds16(ApJ[j] + k0, &As[(j * 256 + tid) * 8]);
#pragma unroll
    for (int j = 0; j < 8; ++j)
      gl_lds16(BpJ[j] + k0, &Bs[(j * 256 + tid) * 8]);
    __syncthreads();
    bf16x8 af[MI][4], bfr[4][4];
#pragma unroll
    for (int i = 0; i < MI; ++i)
#pragma unroll
      for (int kk = 0; kk < 4; ++kk)
        af[i][kk] = rd128(As, wr + i * 16 + l15, kk * 4 + lh);
#pragma unroll
    for (int i = 0; i < 4; ++i)
#pragma unroll
      for (int kk = 0; kk < 4; ++kk)
        bfr[i][kk] = rd128(Bs, wc + i * 16 + l15, kk * 4 + lh);
#pragma unroll
    for (int kk = 0; kk < 4; ++kk)
#pragma unroll
      for (int mi = 0; mi < MI; ++mi)
#pragma unroll
        for (int ni = 0; ni < 4; ++ni)
          acc[mi][ni] = mfma16(af[mi][kk], bfr[ni][kk], acc[mi][ni]);
    __syncthreads();
  }
  if constexpr (MODE == 3) {
#pragma unroll
    for (int mi = 0; mi < MI; ++mi) {
#pragma unroll
      for (int ni = 0; ni < 4; ++ni) {
        int tl = wr + mi * 16 + lh * 4;
        int dl = wc + ni * 16 + l15;
        int colg = bn * 128 + dl;
        int bb = bm >> 5, hh = colg >> 6;
        const float* sp = scvec + (size_t)(bb * 16 + hh) * 2048 + (bm & 31) * 64 + tl;
        float4 rs = *reinterpret_cast<const float4*>(sp);
        unsigned int p0 = f2bf(acc[mi][ni][0] * rs.x) | ((unsigned int)f2bf(acc[mi][ni][1] * rs.y) << 16);
        unsigned int p1 = f2bf(acc[mi][ni][2] * rs.z) | ((unsigned int)f2bf(acc[mi][ni][3] * rs.w) << 16);
        uint2 pk = {p0, p1};
        *reinterpret_cast<uint2*>(&Sh[dl * 64 + (tl ^ ((dl & 7) << 3))]) = pk;
      }
    }
    __syncthreads();
    int dr = tid >> 1, th = (tid & 1) * 32;
    int bb = bm >> 5, tbase = (bm & 31) * 64;
    size_t colg = bn * 128 + dr;
    unsigned short* Vt = (unsigned short*)Cout;
#pragma unroll
    for (int j = 0; j < 4; ++j) {
      int t = th + j * 8;
      int4 v = *reinterpret_cast<const int4*>(&Sh[dr * 64 + (t ^ ((dr & 7) << 3))]);
      *reinterpret_cast<int4*>(&Vt[((size_t)bb * 1024 + colg) * 2048 + tbase + t]) = v;
    }
  } else {
#pragma unroll
    for (int mi = 0; mi < MI; ++mi) {
#pragma unroll
      for (int ni = 0; ni < 4; ++ni) {
        int row0 = bm * TM + wr + mi * 16 + lh * 4;
        int col  = bn * 128 + wc + ni * 16 + l15;
        float bv = (MODE == 2) ? 0.f : bias[col];
#pragma unroll
        for (int r = 0; r < 4; ++r) {
          int row = row0 + r;
          float v = acc[mi][ni][r] + bv;
          if constexpr (MODE == 0) {
            v += resid[(size_t)row * N + col];
            ((float*)Cout)[(size_t)row * N + col] = v;
          } else {
            ((unsigned short*)Cout)[(size_t)row * N + col] = f2bf(v);
            Cout2[(size_t)row * N + col] = f2bf(v * KSCL);
          }
        }
      }
    }
  }
}

// ---------- attention pass A: l_s = sum_{t>=s} exp2(S[t,s]*KSCL); colrcp = 1/l ----------
// Grid 512, 8 waves x 16 s-rows (s-block 128). Long blocks (low sb) dispatch first (LPT).
__global__ __launch_bounds__(512) void attn_stats(const unsigned short* __restrict__ Kb,
                                                  const unsigned short* __restrict__ Kbs,
                                                  float* __restrict__ colrcp) {
  __shared__ __align__(16) unsigned short Kt[2][64 * 64];
  int bid = blockIdx.x;
  int q = bid >> 8, x = (bid >> 5) & 7, bh = bid & 31;
  int b = bh >> 4, h = bh & 15;
  int sb = q ? (15 - x) : x;   // q=0 -> sb 0..7 (longest first)
  int tid = threadIdx.x, lane = tid & 63, w = tid >> 6;
  int l15 = lane & 15, lh = lane >> 4;
  int s0 = sb * 128, sw = s0 + w * 16;
  const unsigned short* Kp  = Kb  + ((size_t)b * 2048) * 1024 + h * 64;
  const unsigned short* Kps = Kbs + ((size_t)b * 2048) * 1024 + h * 64;
  bf16x8 as[2];
#pragma unroll
  for (int kc = 0; kc < 2; ++kc)
    as[kc] = *reinterpret_cast<const bf16x8*>(Kp + (size_t)(sw + l15) * 1024 + kc * 32 + (lh << 3));
  int srow = tid >> 3;
  int sch  = (tid & 7) ^ (srow & 7);
  const unsigned short* ksrc = Kps + (size_t)srow * 1024 + sch * 8;
  gl_lds16(ksrc + (size_t)s0 * 1024, &Kt[0][tid * 8]);
  __syncthreads();
  float l[4] = {0.f, 0.f, 0.f, 0.f};
  int nt = 32 - 2 * sb;
  for (int it = 0; it < nt; ++it) {
    int t0 = s0 + it * 64;
    int cur = it & 1;
    if (it + 1 < nt)
      gl_lds16(ksrc + (size_t)(t0 + 64) * 1024, &Kt[cur ^ 1][tid * 8]);
    if (t0 + 63 >= sw) {               // tile not entirely below diagonal
      bool dmask = (t0 < sw + 16);
#pragma unroll
      for (int tf = 0; tf < 4; ++tf) {
        int tr = tf * 16 + l15;
        bf16x8 bt0 = rdsw64(&Kt[cur][0], tr, lh);
        bf16x8 bt1 = rdsw64(&Kt[cur][0], tr, 4 + lh);
        f32x4 z = {};
        f32x4 sa = mfma16(as[1], bt1, mfma16(as[0], bt0, z));  // D[s][t], lane col = t
        int tg = t0 + tr;
#pragma unroll
        for (int r = 0; r < 4; ++r) {
          float e = fexp2(sa[r]);
          if (dmask) { int sg = sw + lh * 4 + r; e = (tg >= sg) ? e : 0.f; }
          l[r] += e;
        }
      }
    }
    __syncthreads();   // drains gl_lds (vmcnt 0) + releases buffer cur
  }
#pragma unroll
  for (int m = 1; m < 16; m <<= 1)
#pragma unroll
    for (int r = 0; r < 4; ++r)
      l[r] += __shfl_xor(l[r], m);
  if (l15 == 0) {
#pragma unroll
    for (int r = 0; r < 4; ++r)
      colrcp[(size_t)bh * 2048 + sw + lh * 4 + r] = 1.f / l[r];
  }
}

// ---------- attention pass B: O[t,d] = sum_{s<=t} exp2(S*KSCL) * V'[s,d] ----------
// Grid 512, 8 waves x 16 t-rows (t-block 128). LPT: long blocks (high tb) first.
// T15 2-deep pipeline: PV(it-1) overlaps QK(it). Ks double, Vs triple, Pl double.
__global__ __launch_bounds__(512) void attn_pv(const unsigned short* __restrict__ Kb,
                                               const unsigned short* __restrict__ Kbs,
                                               const unsigned short* __restrict__ Vt,
                                               unsigned short* __restrict__ attn) {
  __shared__ __align__(16) unsigned short Ks[2][64 * 64];
  __shared__ __align__(16) unsigned short Vs[3][64 * 64];
  __shared__ __align__(16) unsigned short Pl[8][2][16][68];
  int bid = blockIdx.x;
  int q = bid >> 8, x = (bid >> 5) & 7, bh = bid & 31;
  int b = bh >> 4, h = bh & 15;
  int tb = q ? x : (15 - x);   // q=0 -> tb 15..8 (longest first: LPT)
  int tid = threadIdx.x, lane = tid & 63, w = tid >> 6;
  int l15 = lane & 15, lh = lane >> 4;
  int t0 = tb * 128, tw = t0 + w * 16;
  const unsigned short* Kp  = Kb  + ((size_t)b * 2048) * 1024 + h * 64;
  const unsigned short* Kps = Kbs + ((size_t)b * 2048) * 1024 + h * 64;
  const unsigned short* Vp  = Vt + (size_t)bh * 64 * 2048;
  bf16x8 at[2];
#pragma unroll
  for (int kc = 0; kc < 2; ++kc)
    at[kc] = *reinterpret_cast<const bf16x8*>(Kp + (size_t)(tw + l15) * 1024 + kc * 32 + (lh << 3));
  int srow = tid >> 3;
  int sch  = (tid & 7) ^ (srow & 7);
  const unsigned short* ksrc = Kps + (size_t)srow * 1024 + sch * 8;
  const unsigned short* vsrc = Vp + (size_t)srow * 2048 + sch * 8;
  int nt = 2 * tb + 2;
  gl_lds16(ksrc, &Ks[0][tid * 8]);
  gl_lds16(vsrc, &Vs[0][tid * 8]);
  __syncthreads();
  f32x4 acc[4] = {};
  for (int it = 0; it < nt; ++it) {
    int s0 = it * 64;
    const unsigned short* ksCur = &Ks[it & 1][0];
    if (it + 1 < nt) {
      gl_lds16(ksrc + (size_t)(s0 + 64) * 1024, &Ks[(it + 1) & 1][tid * 8]);
      gl_lds16(vsrc + (s0 + 64), &Vs[(it + 1) % 3][tid * 8]);
    }
    // QK(it): D[s][t] (A = Ks rows s, B = at rows t) -> Pl[w][it&1]
    if (s0 <= tw + 15) {
      bool dmask = (s0 + 63 > tw);
#pragma unroll
      for (int sf = 0; sf < 4; ++sf) {
        int sr = sf * 16 + l15;
        bf16x8 ks0 = rdsw64(ksCur, sr, lh);
        bf16x8 ks1 = rdsw64(ksCur, sr, 4 + lh);
        f32x4 z = {};
        f32x4 sa = mfma16(ks1, at[1], mfma16(ks0, at[0], z));  // D[s][t]
        float pe[4];
#pragma unroll
        for (int r = 0; r < 4; ++r) {
          float p = fexp2(sa[r]);
          if (dmask) {
            int sg = s0 + sf * 16 + lh * 4 + r;
            int tg = tw + l15;
            p = (sg <= tg) ? p : 0.f;
          }
          pe[r] = p;
        }
        unsigned int u0 = cvtpk_bf16(pe[0], pe[1]);
        unsigned int u1 = cvtpk_bf16(pe[2], pe[3]);
        unsigned long long pk = (unsigned long long)u0 | ((unsigned long long)u1 << 32);
        *reinterpret_cast<unsigned long long*>(&Pl[w][it & 1][l15][sf * 16 + lh * 4]) = pk;
      }
    }
    // PV(it-1): D[t][d] (A = Pl[w][prev] rows t, B = Vs[prev] rows d)
    if (it > 0) {
      int pit = it - 1;
      if (pit * 64 <= tw + 15) {
        const unsigned short* vsPrev = &Vs[pit % 3][0];
#pragma unroll
        for (int c2 = 0; c2 < 2; ++c2) {
          bf16x8 pa = *reinterpret_cast<const bf16x8*>(&Pl[w][pit & 1][l15][c2 * 32 + (lh << 3)]);
#pragma unroll
          for (int nf = 0; nf < 4; ++nf) {
            int dr = nf * 16 + l15;
            bf16x8 vb = rdsw64(vsPrev, dr, c2 * 4 + lh);
            acc[nf] = mfma16(pa, vb, acc[nf]);
          }
        }
      }
    }
    __syncthreads();   // drains gl_lds (vmcnt 0) + releases buffers
  }
  // epilogue: PV(nt-1) — buffers stable after final barrier
  {
    int pit = nt - 1;
    if (pit * 64 <= tw + 15) {
      const unsigned short* vsPrev = &Vs[pit % 3][0];
#pragma unroll
      for (int c2 = 0; c2 < 2; ++c2) {
        bf16x8 pa = *reinterpret_cast<const bf16x8*>(&Pl[w][pit & 1][l15][c2 * 32 + (lh << 3)]);
#pragma unroll
        for (int nf = 0; nf < 4; ++nf) {
          int dr = nf * 16 + l15;
          bf16x8 vb = rdsw64(vsPrev, dr, c2 * 4 + lh);
          acc[nf] = mfma16(pa, vb, acc[nf]);
        }
      }
    }
  }
#pragma unroll
  for (int nf = 0; nf < 4; ++nf)
#pragma unroll
    for (int r = 0; r < 4; ++r) {
      int t = tw + lh * 4 + r;
      attn[(size_t)(b * 2048 + t) * 1024 + h * 64 + nf * 16 + l15] = f2bf(acc[nf][r]);
    }
}

extern "C" void kernel_launch(void* const* d_in, const int* in_sizes, int n_in,
                              void* d_out, int out_size, void* d_ws, size_t ws_size,
                              hipStream_t stream) {
  (void)in_sizes; (void)n_in; (void)out_size; (void)ws_size;
  const float* x     = (const float*)d_in[0];
  const float* ln1_g = (const float*)d_in[1];
  const float* ln1_b = (const float*)d_in[2];
  const float* Wk    = (const float*)d_in[3];
  const float* Wv    = (const float*)d_in[4];
  const float* Wproj = (const float*)d_in[5];
  const float* bproj = (const float*)d_in[6];
  const float* ln2_g = (const float*)d_in[7];
  const float* ln2_b = (const float*)d_in[8];
  const float* W1    = (const float*)d_in[9];
  const float* b1    = (const float*)d_in[10];
  const float* W2    = (const float*)d_in[11];
  const float* b2    = (const float*)d_in[12];
  float* out = (float*)d_out;

  char* ws = (char*)d_ws;
  size_t off = 0;
  auto alloc = [&](size_t bytes) { void* p = ws + off; off += (bytes + 255) & ~(size_t)255; return p; };
  unsigned short* bufA = (unsigned short*)alloc((size_t)4096 * 1024 * 2);  // h1 -> attn -> h2
  unsigned short* wk_t = (unsigned short*)alloc((size_t)1024 * 1024 * 2);
  unsigned short* wv_t = (unsigned short*)alloc((size_t)1024 * 1024 * 2);
  unsigned short* wp_t = (unsigned short*)alloc((size_t)1024 * 1024 * 2);
  unsigned short* w1_t = (unsigned short*)alloc((size_t)1024 * 4096 * 2);
  unsigned short* w2_t = (unsigned short*)alloc((size_t)4096 * 1024 * 2);
  unsigned short* Kb   = (unsigned short*)alloc((size_t)4096 * 1024 * 2);
  unsigned short* Kbs  = (unsigned short*)alloc((size_t)4096 * 1024 * 2);
  unsigned short* Vt   = (unsigned short*)alloc((size_t)4096 * 1024 * 2);
  float* colrcp = (float*)alloc((size_t)32 * 2048 * 4);
  float* y      = (float*)alloc((size_t)4096 * 1024 * 4);
  unsigned short* act = (unsigned short*)alloc((size_t)4096 * 4096 * 2);

  dim3 b256(256), b512(512);
  transpose_cvt<<<dim3(2, 32, 16), b256, 0, stream>>>(Wk, wk_t, 1024, 64);
  transpose_cvt<<<dim3(2, 32, 16), b256, 0, stream>>>(Wv, wv_t, 1024, 64);
  transpose_cvt<<<dim3(32, 32, 1), b256, 0, stream>>>(Wproj, wp_t, 1024, 1024);
  transpose_cvt<<<dim3(128, 32, 1), b256, 0, stream>>>(W1, w1_t, 1024, 4096);
  transpose_cvt<<<dim3(32, 128, 1), b256, 0, stream>>>(W2, w2_t, 4096, 1024);

  // LN1
  ln_bf16<<<4096, b256, 0, stream>>>(x, ln1_g, ln1_b, bufA);
  // K (and K*KSCL) = h @ Wk
  gemm_bf16<64, 2><<<512, b256, 0, stream>>>(bufA, wk_t, Kb, Kbs, nullptr, nullptr, nullptr, 4096, 1024, 1024);
  // column softmax denominators
  attn_stats<<<512, b512, 0, stream>>>(Kb, Kbs, colrcp);
  // V' = (h @ Wv) * colrcp, stored transposed [b,h,d,t]
  gemm_bf16<64, 3><<<512, b256, 0, stream>>>(bufA, wv_t, Vt, nullptr, nullptr, nullptr, colrcp, 4096, 1024, 1024);
  // O = exp2(S*KSCL) @ V'
  attn_pv<<<512, b512, 0, stream>>>(Kb, Kbs, Vt, bufA);
  // y = x + O @ Wproj + bproj
  gemm_bf16<64, 0><<<512, b256, 0, stream>>>(bufA, wp_t, y, nullptr, bproj, x, nullptr, 4096, 1024, 1024);
  // LN2
  ln_bf16<<<4096, b256, 0, stream>>>(y, ln2_g, ln2_b, bufA);
  // act = relu(h2 @ W1 + b1)   -- 256x256 8-phase kernel
  gemm256_relu<<<256, dim3(512), 0, stream>>>(bufA, w1_t, act, b1, 4096, 4096, 1024);
  // out = y + act @ W2 + b2
  gemm_bf16<64, 0><<<512, b256, 0, stream>>>(act, w2_t, out, nullptr, b2, y, nullptr, 4096, 1024, 4096);
}

// Round 14
// 231.211 us; speedup vs baseline: 1.0386x; 1.0386x over previous
//
#include <hip/hip_runtime.h>

using bf16x8 = __attribute__((ext_vector_type(8))) __bf16;
using f32x4  = __attribute__((ext_vector_type(4))) float;

__device__ __forceinline__ f32x4 mfma16(bf16x8 a, bf16x8 b, f32x4 c) {
  return __builtin_amdgcn_mfma_f32_16x16x32_bf16(a, b, c, 0, 0, 0);
}

__device__ __forceinline__ unsigned short f2bf(float f) {
  union { float f; unsigned int u; } x; x.f = f;
  unsigned int u = x.u + 0x7FFFu + ((x.u >> 16) & 1u);
  return (unsigned short)(u >> 16);
}

__device__ __forceinline__ unsigned int cvtpk_bf16(float lo, float hi) {
  unsigned int r;
  asm("v_cvt_pk_bf16_f32 %0, %1, %2" : "=v"(r) : "v"(lo), "v"(hi));
  return r;
}

// raw v_exp_f32: inputs bounded (|S*KSCL| < ~1.3) so no libm range fixup needed
__device__ __forceinline__ float fexp2(float x) {
#if __has_builtin(__builtin_amdgcn_exp2f)
  return __builtin_amdgcn_exp2f(x);
#else
  float r; asm("v_exp_f32 %0, %1" : "=v"(r) : "v"(x)); return r;
#endif
}

__device__ __forceinline__ void gl_lds16(const unsigned short* g, unsigned short* l) {
  __builtin_amdgcn_global_load_lds(
      (__attribute__((address_space(1))) void*)(g),
      (__attribute__((address_space(3))) void*)(l), 16, 0, 0);
}

// swizzled read from a 64-elem-row LDS tile staged with chunk ^= (row&7)
__device__ __forceinline__ bf16x8 rdsw64(const unsigned short* base, int r, int ch) {
  int c = ch ^ (r & 7);
  return *reinterpret_cast<const bf16x8*>(base + ((size_t)r * 8 + c) * 8);
}

// ---------- transpose + f32->bf16: out[b][c][r] = in[b][r][c] ----------
__global__ __launch_bounds__(256) void transpose_cvt(const float* __restrict__ in,
                                                     unsigned short* __restrict__ out,
                                                     int R, int C) {
  __shared__ float t[32][33];
  int b = blockIdx.z;
  const float* inb = in + (size_t)b * R * C;
  unsigned short* outb = out + (size_t)b * R * C;
  int tx = threadIdx.x & 31, ty = threadIdx.x >> 5;
  int c0 = blockIdx.x * 32, r0 = blockIdx.y * 32;
#pragma unroll
  for (int i = 0; i < 4; ++i)
    t[ty + i * 8][tx] = inb[(size_t)(r0 + ty + i * 8) * C + c0 + tx];
  __syncthreads();
#pragma unroll
  for (int i = 0; i < 4; ++i)
    outb[(size_t)(c0 + ty + i * 8) * R + r0 + tx] = f2bf(t[tx][ty + i * 8]);
}

// ---------- layernorm (rows of 1024) f32 -> bf16 ----------
__global__ __launch_bounds__(256) void ln_bf16(const float* __restrict__ x,
                                               const float* __restrict__ g,
                                               const float* __restrict__ bta,
                                               unsigned short* __restrict__ out) {
  int row = blockIdx.x, tid = threadIdx.x;
  float4 v = reinterpret_cast<const float4*>(x + (size_t)row * 1024)[tid];
  float s = v.x + v.y + v.z + v.w;
  float s2 = v.x * v.x + v.y * v.y + v.z * v.z + v.w * v.w;
#pragma unroll
  for (int m = 1; m < 64; m <<= 1) { s += __shfl_xor(s, m); s2 += __shfl_xor(s2, m); }
  __shared__ float red[8];
  int w = tid >> 6;
  if ((tid & 63) == 0) { red[w] = s; red[w + 4] = s2; }
  __syncthreads();
  s  = red[0] + red[1] + red[2] + red[3];
  s2 = red[4] + red[5] + red[6] + red[7];
  float mean = s * (1.f / 1024.f);
  float var  = s2 * (1.f / 1024.f) - mean * mean;
  float rstd = rsqrtf(var + 1e-5f);
  float4 gv = reinterpret_cast<const float4*>(g)[tid];
  float4 bv = reinterpret_cast<const float4*>(bta)[tid];
  ushort4 o;
  o.x = f2bf((v.x - mean) * rstd * gv.x + bv.x);
  o.y = f2bf((v.y - mean) * rstd * gv.y + bv.y);
  o.z = f2bf((v.z - mean) * rstd * gv.z + bv.z);
  o.w = f2bf((v.w - mean) * rstd * gv.w + bv.w);
  reinterpret_cast<ushort4*>(out + (size_t)row * 1024)[tid] = o;
}

// ================= 256x256 8-phase GEMM (MLP1): C=relu(A*Bt^T+bias), bf16 out =====
__device__ __forceinline__ void stage_half(const unsigned short* gbase, int K,
                                           unsigned short* lds, int tid) {
#pragma unroll
  for (int j = 0; j < 2; ++j) {
    int lr = j * 64 + (tid >> 3);
    int c  = (tid & 7) ^ (lr & 7);
    gl_lds16(gbase + (size_t)lr * K + c * 8, lds + (size_t)(j * 512 + tid) * 8);
  }
}

__device__ __forceinline__ bf16x8 rdfrag(const unsigned short* base, int r, int k) {
  return *reinterpret_cast<const bf16x8*>(base + ((size_t)r * 8 + (k ^ (r & 7))) * 8);
}

__global__ __launch_bounds__(512, 2) void gemm256_relu(const unsigned short* __restrict__ A,
                                                       const unsigned short* __restrict__ Bt,
                                                       unsigned short* __restrict__ C,
                                                       const float* __restrict__ bias,
                                                       int M, int N, int K) {
  __shared__ __align__(16) unsigned short LA[2][256 * 64];
  __shared__ __align__(16) unsigned short LB[2][256 * 64];
  int tid = threadIdx.x, lane = tid & 63, w = tid >> 6;
  int l15 = lane & 15, lh = lane >> 4;
  int wr = (w >> 2) * 128, wc = (w & 3) * 64;
  int bid = blockIdx.x;
  int xcd = bid & 7, g = bid >> 3;
  int bm = (xcd >> 1) * 4 + (g >> 3);
  int bn = (xcd & 1) * 8 + (g & 7);
  const unsigned short* Ab = A + (size_t)(bm * 256) * K;
  const unsigned short* Bb = Bt + (size_t)(bn * 256) * K;
  f32x4 acc[8][4] = {};
  int NT = K >> 6;
  stage_half(Ab, K, &LA[0][0], tid);
  stage_half(Ab + (size_t)128 * K, K, &LA[0][128 * 64], tid);
  stage_half(Bb, K, &LB[0][0], tid);
  stage_half(Bb + (size_t)128 * K, K, &LB[0][128 * 64], tid);
  asm volatile("s_waitcnt vmcnt(0)" ::: "memory");
  __builtin_amdgcn_s_barrier();
  for (int t = 0; t < NT; ++t) {
    int cur = t & 1;
    const unsigned short* la = &LA[cur][0];
    const unsigned short* lb = &LB[cur][0];
    unsigned short* na = &LA[cur ^ 1][0];
    unsigned short* nb = &LB[cur ^ 1][0];
    int k0n = (t + 1) << 6;
    bool more = (t + 1 < NT);
    bf16x8 bfr[4][2];
#pragma unroll
    for (int q = 0; q < 4; ++q) {
      if (more) {
        if (q == 0)      stage_half(Ab + k0n, K, na, tid);
        else if (q == 1) stage_half(Ab + (size_t)128 * K + k0n, K, na + 128 * 64, tid);
        else if (q == 2) stage_half(Bb + k0n, K, nb, tid);
        else             stage_half(Bb + (size_t)128 * K + k0n, K, nb + 128 * 64, tid);
      }
      if (q == 0) {
        if (more) asm volatile("s_waitcnt vmcnt(2)" ::: "memory");
        else      asm volatile("s_waitcnt vmcnt(0)" ::: "memory");
        __builtin_amdgcn_s_barrier();
      }
      bf16x8 aq[2][2];
#pragma unroll
      for (int i = 0; i < 2; ++i)
#pragma unroll
        for (int kk = 0; kk < 2; ++kk)
          aq[i][kk] = rdfrag(la, wr + q * 32 + i * 16 + l15, kk * 4 + lh);
      if (q == 0) {
#pragma unroll
        for (int ni = 0; ni < 4; ++ni)
#pragma unroll
          for (int kk = 0; kk < 2; ++kk)
            bfr[ni][kk] = rdfrag(lb, wc + ni * 16 + l15, kk * 4 + lh);
      }
      if (q != 0) __builtin_amdgcn_s_barrier();
      __builtin_amdgcn_s_setprio(1);
#pragma unroll
      for (int kk = 0; kk < 2; ++kk)
#pragma unroll
        for (int i = 0; i < 2; ++i)
#pragma unroll
          for (int ni = 0; ni < 4; ++ni)
            acc[q * 2 + i][ni] = mfma16(aq[i][kk], bfr[ni][kk], acc[q * 2 + i][ni]);
      __builtin_amdgcn_s_setprio(0);
      __builtin_amdgcn_s_barrier();
    }
  }
#pragma unroll
  for (int mi = 0; mi < 8; ++mi)
#pragma unroll
    for (int ni = 0; ni < 4; ++ni) {
      int row0 = bm * 256 + wr + mi * 16 + lh * 4;
      int col  = bn * 256 + wc + ni * 16 + l15;
      float bv = bias[col];
#pragma unroll
      for (int r = 0; r < 4; ++r) {
        float v = fmaxf(acc[mi][ni][r] + bv, 0.f);
        C[(size_t)(row0 + r) * N + col] = f2bf(v);
      }
    }
}

// ---------- bf16 MFMA GEMM: C[M][N] = A[M][K] * Bt[N][K]^T ----------
// BK=64, DOUBLE-buffered with counted vmcnt + raw barriers (loads stay in flight
// across the compute phase). T2 swizzle both sides (chunk ^= row&7). TM x 128, 4 waves.
#define KSCL 0.04508422f  /* (1/32) * log2(e): S*KSCL feeds exp2 */

template<int TM, int MODE>
__global__ __launch_bounds__(256) void gemm_bf16(const unsigned short* __restrict__ A,
                                                 const unsigned short* __restrict__ Bt,
                                                 void* __restrict__ Cout,
                                                 unsigned short* __restrict__ Cout2,
                                                 const float* __restrict__ bias,
                                                 const float* __restrict__ resid,
                                                 const float* __restrict__ scvec,
                                                 int M, int N, int K) {
  constexpr int MI  = TM / 32;
  constexpr int ALD = TM / 32;       // A gl_lds per thread per tile
  constexpr int NLD = ALD + 4;       // total loads/thread/tile
  __shared__ __align__(16) unsigned short Sh[2][(TM + 128) * 64];
  int tid = threadIdx.x;
  int lane = tid & 63, w = tid >> 6;
  int l15 = lane & 15, lh = lane >> 4;
  int wr = (w >> 1) * (TM / 2), wc = (w & 1) * 64;
  int nblk = N >> 7;
  int rows = M / TM;
  int bm, bn;
  if (nblk == 8 && (rows & 7) == 0) {
    int bid = blockIdx.x;
    int xcd = bid & 7, g = bid >> 3;
    bm = xcd * (rows >> 3) + (g >> 3);
    bn = g & 7;
  } else {
    bm = blockIdx.x / nblk; bn = blockIdx.x % nblk;
  }
  // per-thread staging sources (pre-swizzled global, linear LDS dest)
  const unsigned short* Asrc[ALD];
  const unsigned short* Bsrc[4];
#pragma unroll
  for (int j = 0; j < ALD; ++j) {
    int row = j * 32 + (tid >> 3);
    int ch  = (tid & 7) ^ (row & 7);
    Asrc[j] = A + (size_t)(bm * TM + row) * K + ch * 8;
  }
#pragma unroll
  for (int j = 0; j < 4; ++j) {
    int row = j * 32 + (tid >> 3);
    int ch  = (tid & 7) ^ (row & 7);
    Bsrc[j] = Bt + (size_t)(bn * 128 + row) * K + ch * 8;
  }
  f32x4 acc[MI][4] = {};
  int NT = K >> 6;
  // prologue: tile 0 -> buf 0
  {
#pragma unroll
    for (int j = 0; j < ALD; ++j) gl_lds16(Asrc[j], &Sh[0][(j * 256 + tid) * 8]);
#pragma unroll
    for (int j = 0; j < 4; ++j)  gl_lds16(Bsrc[j], &Sh[0][TM * 64 + (j * 256 + tid) * 8]);
  }
  for (int t = 0; t < NT; ++t) {
    int cur = t & 1;
    const unsigned short* Asc = &Sh[cur][0];
    const unsigned short* Bsc = &Sh[cur][TM * 64];
    if (t + 1 < NT) {
      int k0 = (t + 1) << 6;
      unsigned short* Asn = &Sh[cur ^ 1][0];
      unsigned short* Bsn = &Sh[cur ^ 1][TM * 64];
#pragma unroll
      for (int j = 0; j < ALD; ++j) gl_lds16(Asrc[j] + k0, Asn + (j * 256 + tid) * 8);
#pragma unroll
      for (int j = 0; j < 4; ++j)  gl_lds16(Bsrc[j] + k0, Bsn + (j * 256 + tid) * 8);
      asm volatile("s_waitcnt vmcnt(%0)" :: "i"(NLD) : "memory");  // tile t landed; t+1 in flight
    } else {
      asm volatile("s_waitcnt vmcnt(0)" ::: "memory");
    }
    __builtin_amdgcn_s_barrier();        // all waves' tile-t loads visible
    bf16x8 af[MI][2], bfr[4][2];
#pragma unroll
    for (int i = 0; i < MI; ++i)
#pragma unroll
      for (int kk = 0; kk < 2; ++kk)
        af[i][kk] = rdsw64(Asc, wr + i * 16 + l15, kk * 4 + lh);
#pragma unroll
    for (int i = 0; i < 4; ++i)
#pragma unroll
      for (int kk = 0; kk < 2; ++kk)
        bfr[i][kk] = rdsw64(Bsc, wc + i * 16 + l15, kk * 4 + lh);
    __builtin_amdgcn_s_setprio(1);
#pragma unroll
    for (int kk = 0; kk < 2; ++kk)
#pragma unroll
      for (int mi = 0; mi < MI; ++mi)
#pragma unroll
        for (int ni = 0; ni < 4; ++ni)
          acc[mi][ni] = mfma16(af[mi][kk], bfr[ni][kk], acc[mi][ni]);
    __builtin_amdgcn_s_setprio(0);
    __builtin_amdgcn_s_barrier();        // reads of buf cur done before it is restaged
  }
  unsigned short* Sh0 = &Sh[0][0];
  if constexpr (MODE == 3) {
#pragma unroll
    for (int mi = 0; mi < MI; ++mi) {
#pragma unroll
      for (int ni = 0; ni < 4; ++ni) {
        int tl = wr + mi * 16 + lh * 4;
        int dl = wc + ni * 16 + l15;
        int colg = bn * 128 + dl;
        int bb = bm >> 5, hh = colg >> 6;
        const float* sp = scvec + (size_t)(bb * 16 + hh) * 2048 + (bm & 31) * 64 + tl;
        float4 rs = *reinterpret_cast<const float4*>(sp);
        unsigned int p0 = f2bf(acc[mi][ni][0] * rs.x) | ((unsigned int)f2bf(acc[mi][ni][1] * rs.y) << 16);
        unsigned int p1 = f2bf(acc[mi][ni][2] * rs.z) | ((unsigned int)f2bf(acc[mi][ni][3] * rs.w) << 16);
        uint2 pk = {p0, p1};
        *reinterpret_cast<uint2*>(&Sh0[dl * 64 + (tl ^ ((dl & 7) << 3))]) = pk;
      }
    }
    __syncthreads();
    int dr = tid >> 1, th = (tid & 1) * 32;
    int bb = bm >> 5, tbase = (bm & 31) * 64;
    size_t colg = bn * 128 + dr;
    unsigned short* Vt = (unsigned short*)Cout;
#pragma unroll
    for (int j = 0; j < 4; ++j) {
      int t = th + j * 8;
      int4 v = *reinterpret_cast<const int4*>(&Sh0[dr * 64 + (t ^ ((dr & 7) << 3))]);
      *reinterpret_cast<int4*>(&Vt[((size_t)bb * 1024 + colg) * 2048 + tbase + t]) = v;
    }
  } else {
#pragma unroll
    for (int mi = 0; mi < MI; ++mi) {
#pragma unroll
      for (int ni = 0; ni < 4; ++ni) {
        int row0 = bm * TM + wr + mi * 16 + lh * 4;
        int col  = bn * 128 + wc + ni * 16 + l15;
        float bv = (MODE == 2) ? 0.f : bias[col];
#pragma unroll
        for (int r = 0; r < 4; ++r) {
          int row = row0 + r;
          float v = acc[mi][ni][r] + bv;
          if constexpr (MODE == 0) {
            v += resid[(size_t)row * N + col];
            ((float*)Cout)[(size_t)row * N + col] = v;
          } else {
            ((unsigned short*)Cout)[(size_t)row * N + col] = f2bf(v);
            Cout2[(size_t)row * N + col] = f2bf(v * KSCL);
          }
        }
      }
    }
  }
}

// ---------- attention pass A: l_s = sum_{t>=s} exp2(S[t,s]*KSCL); colrcp = 1/l ----------
// Grid 512, 8 waves x 16 s-rows (s-block 128). Long blocks (low sb) dispatch first (LPT).
__global__ __launch_bounds__(512) void attn_stats(const unsigned short* __restrict__ Kb,
                                                  const unsigned short* __restrict__ Kbs,
                                                  float* __restrict__ colrcp) {
  __shared__ __align__(16) unsigned short Kt[2][64 * 64];
  int bid = blockIdx.x;
  int q = bid >> 8, x = (bid >> 5) & 7, bh = bid & 31;
  int b = bh >> 4, h = bh & 15;
  int sb = q ? (15 - x) : x;   // q=0 -> sb 0..7 (longest first)
  int tid = threadIdx.x, lane = tid & 63, w = tid >> 6;
  int l15 = lane & 15, lh = lane >> 4;
  int s0 = sb * 128, sw = s0 + w * 16;
  const unsigned short* Kp  = Kb  + ((size_t)b * 2048) * 1024 + h * 64;
  const unsigned short* Kps = Kbs + ((size_t)b * 2048) * 1024 + h * 64;
  bf16x8 as[2];
#pragma unroll
  for (int kc = 0; kc < 2; ++kc)
    as[kc] = *reinterpret_cast<const bf16x8*>(Kp + (size_t)(sw + l15) * 1024 + kc * 32 + (lh << 3));
  int srow = tid >> 3;
  int sch  = (tid & 7) ^ (srow & 7);
  const unsigned short* ksrc = Kps + (size_t)srow * 1024 + sch * 8;
  gl_lds16(ksrc + (size_t)s0 * 1024, &Kt[0][tid * 8]);
  __syncthreads();
  float l[4] = {0.f, 0.f, 0.f, 0.f};
  int nt = 32 - 2 * sb;
  for (int it = 0; it < nt; ++it) {
    int t0 = s0 + it * 64;
    int cur = it & 1;
    if (it + 1 < nt)
      gl_lds16(ksrc + (size_t)(t0 + 64) * 1024, &Kt[cur ^ 1][tid * 8]);
    if (t0 + 63 >= sw) {               // tile not entirely below diagonal
      bool dmask = (t0 < sw + 16);
#pragma unroll
      for (int tf = 0; tf < 4; ++tf) {
        int tr = tf * 16 + l15;
        bf16x8 bt0 = rdsw64(&Kt[cur][0], tr, lh);
        bf16x8 bt1 = rdsw64(&Kt[cur][0], tr, 4 + lh);
        f32x4 z = {};
        f32x4 sa = mfma16(as[1], bt1, mfma16(as[0], bt0, z));  // D[s][t], lane col = t
        int tg = t0 + tr;
#pragma unroll
        for (int r = 0; r < 4; ++r) {
          float e = fexp2(sa[r]);
          if (dmask) { int sg = sw + lh * 4 + r; e = (tg >= sg) ? e : 0.f; }
          l[r] += e;
        }
      }
    }
    __syncthreads();   // drains gl_lds (vmcnt 0) + releases buffer cur
  }
#pragma unroll
  for (int m = 1; m < 16; m <<= 1)
#pragma unroll
    for (int r = 0; r < 4; ++r)
      l[r] += __shfl_xor(l[r], m);
  if (l15 == 0) {
#pragma unroll
    for (int r = 0; r < 4; ++r)
      colrcp[(size_t)bh * 2048 + sw + lh * 4 + r] = 1.f / l[r];
  }
}

// ---------- attention pass B: O[t,d] = sum_{s<=t} exp2(S*KSCL) * V'[s,d] ----------
// Grid 512, 8 waves x 16 t-rows (t-block 128). LPT: long blocks (high tb) first.
// T15 2-deep pipeline: PV(it-1) overlaps QK(it). Ks double, Vs triple, Pl double.
__global__ __launch_bounds__(512) void attn_pv(const unsigned short* __restrict__ Kb,
                                               const unsigned short* __restrict__ Kbs,
                                               const unsigned short* __restrict__ Vt,
                                               unsigned short* __restrict__ attn) {
  __shared__ __align__(16) unsigned short Ks[2][64 * 64];
  __shared__ __align__(16) unsigned short Vs[3][64 * 64];
  __shared__ __align__(16) unsigned short Pl[8][2][16][68];
  int bid = blockIdx.x;
  int q = bid >> 8, x = (bid >> 5) & 7, bh = bid & 31;
  int b = bh >> 4, h = bh & 15;
  int tb = q ? x : (15 - x);   // q=0 -> tb 15..8 (longest first: LPT)
  int tid = threadIdx.x, lane = tid & 63, w = tid >> 6;
  int l15 = lane & 15, lh = lane >> 4;
  int t0 = tb * 128, tw = t0 + w * 16;
  const unsigned short* Kp  = Kb  + ((size_t)b * 2048) * 1024 + h * 64;
  const unsigned short* Kps = Kbs + ((size_t)b * 2048) * 1024 + h * 64;
  const unsigned short* Vp  = Vt + (size_t)bh * 64 * 2048;
  bf16x8 at[2];
#pragma unroll
  for (int kc = 0; kc < 2; ++kc)
    at[kc] = *reinterpret_cast<const bf16x8*>(Kp + (size_t)(tw + l15) * 1024 + kc * 32 + (lh << 3));
  int srow = tid >> 3;
  int sch  = (tid & 7) ^ (srow & 7);
  const unsigned short* ksrc = Kps + (size_t)srow * 1024 + sch * 8;
  const unsigned short* vsrc = Vp + (size_t)srow * 2048 + sch * 8;
  int nt = 2 * tb + 2;
  gl_lds16(ksrc, &Ks[0][tid * 8]);
  gl_lds16(vsrc, &Vs[0][tid * 8]);
  __syncthreads();
  f32x4 acc[4] = {};
  for (int it = 0; it < nt; ++it) {
    int s0 = it * 64;
    const unsigned short* ksCur = &Ks[it & 1][0];
    if (it + 1 < nt) {
      gl_lds16(ksrc + (size_t)(s0 + 64) * 1024, &Ks[(it + 1) & 1][tid * 8]);
      gl_lds16(vsrc + (s0 + 64), &Vs[(it + 1) % 3][tid * 8]);
    }
    // QK(it): D[s][t] (A = Ks rows s, B = at rows t) -> Pl[w][it&1]
    if (s0 <= tw + 15) {
      bool dmask = (s0 + 63 > tw);
#pragma unroll
      for (int sf = 0; sf < 4; ++sf) {
        int sr = sf * 16 + l15;
        bf16x8 ks0 = rdsw64(ksCur, sr, lh);
        bf16x8 ks1 = rdsw64(ksCur, sr, 4 + lh);
        f32x4 z = {};
        f32x4 sa = mfma16(ks1, at[1], mfma16(ks0, at[0], z));  // D[s][t]
        float pe[4];
#pragma unroll
        for (int r = 0; r < 4; ++r) {
          float p = fexp2(sa[r]);
          if (dmask) {
            int sg = s0 + sf * 16 + lh * 4 + r;
            int tg = tw + l15;
            p = (sg <= tg) ? p : 0.f;
          }
          pe[r] = p;
        }
        unsigned int u0 = cvtpk_bf16(pe[0], pe[1]);
        unsigned int u1 = cvtpk_bf16(pe[2], pe[3]);
        unsigned long long pk = (unsigned long long)u0 | ((unsigned long long)u1 << 32);
        *reinterpret_cast<unsigned long long*>(&Pl[w][it & 1][l15][sf * 16 + lh * 4]) = pk;
      }
    }
    // PV(it-1): D[t][d] (A = Pl[w][prev] rows t, B = Vs[prev] rows d)
    if (it > 0) {
      int pit = it - 1;
      if (pit * 64 <= tw + 15) {
        const unsigned short* vsPrev = &Vs[pit % 3][0];
#pragma unroll
        for (int c2 = 0; c2 < 2; ++c2) {
          bf16x8 pa = *reinterpret_cast<const bf16x8*>(&Pl[w][pit & 1][l15][c2 * 32 + (lh << 3)]);
#pragma unroll
          for (int nf = 0; nf < 4; ++nf) {
            int dr = nf * 16 + l15;
            bf16x8 vb = rdsw64(vsPrev, dr, c2 * 4 + lh);
            acc[nf] = mfma16(pa, vb, acc[nf]);
          }
        }
      }
    }
    __syncthreads();   // drains gl_lds (vmcnt 0) + releases buffers
  }
  // epilogue: PV(nt-1) — buffers stable after final barrier
  {
    int pit = nt - 1;
    if (pit * 64 <= tw + 15) {
      const unsigned short* vsPrev = &Vs[pit % 3][0];
#pragma unroll
      for (int c2 = 0; c2 < 2; ++c2) {
        bf16x8 pa = *reinterpret_cast<const bf16x8*>(&Pl[w][pit & 1][l15][c2 * 32 + (lh << 3)]);
#pragma unroll
        for (int nf = 0; nf < 4; ++nf) {
          int dr = nf * 16 + l15;
          bf16x8 vb = rdsw64(vsPrev, dr, c2 * 4 + lh);
          acc[nf] = mfma16(pa, vb, acc[nf]);
        }
      }
    }
  }
#pragma unroll
  for (int nf = 0; nf < 4; ++nf)
#pragma unroll
    for (int r = 0; r < 4; ++r) {
      int t = tw + lh * 4 + r;
      attn[(size_t)(b * 2048 + t) * 1024 + h * 64 + nf * 16 + l15] = f2bf(acc[nf][r]);
    }
}

extern "C" void kernel_launch(void* const* d_in, const int* in_sizes, int n_in,
                              void* d_out, int out_size, void* d_ws, size_t ws_size,
                              hipStream_t stream) {
  (void)in_sizes; (void)n_in; (void)out_size; (void)ws_size;
  const float* x     = (const float*)d_in[0];
  const float* ln1_g = (const float*)d_in[1];
  const float* ln1_b = (const float*)d_in[2];
  const float* Wk    = (const float*)d_in[3];
  const float* Wv    = (const float*)d_in[4];
  const float* Wproj = (const float*)d_in[5];
  const float* bproj = (const float*)d_in[6];
  const float* ln2_g = (const float*)d_in[7];
  const float* ln2_b = (const float*)d_in[8];
  const float* W1    = (const float*)d_in[9];
  const float* b1    = (const float*)d_in[10];
  const float* W2    = (const float*)d_in[11];
  const float* b2    = (const float*)d_in[12];
  float* out = (float*)d_out;

  char* ws = (char*)d_ws;
  size_t off = 0;
  auto alloc = [&](size_t bytes) { void* p = ws + off; off += (bytes + 255) & ~(size_t)255; return p; };
  unsigned short* bufA = (unsigned short*)alloc((size_t)4096 * 1024 * 2);  // h1 -> attn -> h2
  unsigned short* wk_t = (unsigned short*)alloc((size_t)1024 * 1024 * 2);
  unsigned short* wv_t = (unsigned short*)alloc((size_t)1024 * 1024 * 2);
  unsigned short* wp_t = (unsigned short*)alloc((size_t)1024 * 1024 * 2);
  unsigned short* w1_t = (unsigned short*)alloc((size_t)1024 * 4096 * 2);
  unsigned short* w2_t = (unsigned short*)alloc((size_t)4096 * 1024 * 2);
  unsigned short* Kb   = (unsigned short*)alloc((size_t)4096 * 1024 * 2);
  unsigned short* Kbs  = (unsigned short*)alloc((size_t)4096 * 1024 * 2);
  unsigned short* Vt   = (unsigned short*)alloc((size_t)4096 * 1024 * 2);
  float* colrcp = (float*)alloc((size_t)32 * 2048 * 4);
  float* y      = (float*)alloc((size_t)4096 * 1024 * 4);
  unsigned short* act = (unsigned short*)alloc((size_t)4096 * 4096 * 2);

  dim3 b256(256), b512(512);
  transpose_cvt<<<dim3(2, 32, 16), b256, 0, stream>>>(Wk, wk_t, 1024, 64);
  transpose_cvt<<<dim3(2, 32, 16), b256, 0, stream>>>(Wv, wv_t, 1024, 64);
  transpose_cvt<<<dim3(32, 32, 1), b256, 0, stream>>>(Wproj, wp_t, 1024, 1024);
  transpose_cvt<<<dim3(128, 32, 1), b256, 0, stream>>>(W1, w1_t, 1024, 4096);
  transpose_cvt<<<dim3(32, 128, 1), b256, 0, stream>>>(W2, w2_t, 4096, 1024);

  // LN1
  ln_bf16<<<4096, b256, 0, stream>>>(x, ln1_g, ln1_b, bufA);
  // K (and K*KSCL) = h @ Wk
  gemm_bf16<64, 2><<<512, b256, 0, stream>>>(bufA, wk_t, Kb, Kbs, nullptr, nullptr, nullptr, 4096, 1024, 1024);
  // column softmax denominators
  attn_stats<<<512, b512, 0, stream>>>(Kb, Kbs, colrcp);
  // V' = (h @ Wv) * colrcp, stored transposed [b,h,d,t]
  gemm_bf16<64, 3><<<512, b256, 0, stream>>>(bufA, wv_t, Vt, nullptr, nullptr, nullptr, colrcp, 4096, 1024, 1024);
  // O = exp2(S*KSCL) @ V'
  attn_pv<<<512, b512, 0, stream>>>(Kb, Kbs, Vt, bufA);
  // y = x + O @ Wproj + bproj
  gemm_bf16<64, 0><<<512, b256, 0, stream>>>(bufA, wp_t, y, nullptr, bproj, x, nullptr, 4096, 1024, 1024);
  // LN2
  ln_bf16<<<4096, b256, 0, stream>>>(y, ln2_g, ln2_b, bufA);
  // act = relu(h2 @ W1 + b1)   -- 256x256 8-phase kernel
  gemm256_relu<<<256, dim3(512), 0, stream>>>(bufA, w1_t, act, b1, 4096, 4096, 1024);
  // out = y + act @ W2 + b2
  gemm_bf16<64, 0><<<512, b256, 0, stream>>>(act, w2_t, out, nullptr, b2, y, nullptr, 4096, 1024, 4096);
}

// Round 15
// 230.903 us; speedup vs baseline: 1.0400x; 1.0013x over previous
//
#include <hip/hip_runtime.h>

using bf16x8 = __attribute__((ext_vector_type(8))) __bf16;
using f32x4  = __attribute__((ext_vector_type(4))) float;

__device__ __forceinline__ f32x4 mfma16(bf16x8 a, bf16x8 b, f32x4 c) {
  return __builtin_amdgcn_mfma_f32_16x16x32_bf16(a, b, c, 0, 0, 0);
}

__device__ __forceinline__ unsigned short f2bf(float f) {
  union { float f; unsigned int u; } x; x.f = f;
  unsigned int u = x.u + 0x7FFFu + ((x.u >> 16) & 1u);
  return (unsigned short)(u >> 16);
}

__device__ __forceinline__ unsigned int cvtpk_bf16(float lo, float hi) {
  unsigned int r;
  asm("v_cvt_pk_bf16_f32 %0, %1, %2" : "=v"(r) : "v"(lo), "v"(hi));
  return r;
}

// raw v_exp_f32: inputs bounded (|S*KSCL| < ~1.3) so no libm range fixup needed
__device__ __forceinline__ float fexp2(float x) {
#if __has_builtin(__builtin_amdgcn_exp2f)
  return __builtin_amdgcn_exp2f(x);
#else
  float r; asm("v_exp_f32 %0, %1" : "=v"(r) : "v"(x)); return r;
#endif
}

__device__ __forceinline__ void gl_lds16(const unsigned short* g, unsigned short* l) {
  __builtin_amdgcn_global_load_lds(
      (__attribute__((address_space(1))) void*)(g),
      (__attribute__((address_space(3))) void*)(l), 16, 0, 0);
}

// swizzled read from a 64-elem-row LDS tile staged with chunk ^= (row&7)
__device__ __forceinline__ bf16x8 rdsw64(const unsigned short* base, int r, int ch) {
  int c = ch ^ (r & 7);
  return *reinterpret_cast<const bf16x8*>(base + ((size_t)r * 8 + c) * 8);
}

// ---------- transpose + f32->bf16: out[b][c][r] = in[b][r][c] ----------
__global__ __launch_bounds__(256) void transpose_cvt(const float* __restrict__ in,
                                                     unsigned short* __restrict__ out,
                                                     int R, int C) {
  __shared__ float t[32][33];
  int b = blockIdx.z;
  const float* inb = in + (size_t)b * R * C;
  unsigned short* outb = out + (size_t)b * R * C;
  int tx = threadIdx.x & 31, ty = threadIdx.x >> 5;
  int c0 = blockIdx.x * 32, r0 = blockIdx.y * 32;
#pragma unroll
  for (int i = 0; i < 4; ++i)
    t[ty + i * 8][tx] = inb[(size_t)(r0 + ty + i * 8) * C + c0 + tx];
  __syncthreads();
#pragma unroll
  for (int i = 0; i < 4; ++i)
    outb[(size_t)(c0 + ty + i * 8) * R + r0 + tx] = f2bf(t[tx][ty + i * 8]);
}

// ---------- layernorm (rows of 1024) f32 -> bf16 ----------
__global__ __launch_bounds__(256) void ln_bf16(const float* __restrict__ x,
                                               const float* __restrict__ g,
                                               const float* __restrict__ bta,
                                               unsigned short* __restrict__ out) {
  int row = blockIdx.x, tid = threadIdx.x;
  float4 v = reinterpret_cast<const float4*>(x + (size_t)row * 1024)[tid];
  float s = v.x + v.y + v.z + v.w;
  float s2 = v.x * v.x + v.y * v.y + v.z * v.z + v.w * v.w;
#pragma unroll
  for (int m = 1; m < 64; m <<= 1) { s += __shfl_xor(s, m); s2 += __shfl_xor(s2, m); }
  __shared__ float red[8];
  int w = tid >> 6;
  if ((tid & 63) == 0) { red[w] = s; red[w + 4] = s2; }
  __syncthreads();
  s  = red[0] + red[1] + red[2] + red[3];
  s2 = red[4] + red[5] + red[6] + red[7];
  float mean = s * (1.f / 1024.f);
  float var  = s2 * (1.f / 1024.f) - mean * mean;
  float rstd = rsqrtf(var + 1e-5f);
  float4 gv = reinterpret_cast<const float4*>(g)[tid];
  float4 bv = reinterpret_cast<const float4*>(bta)[tid];
  ushort4 o;
  o.x = f2bf((v.x - mean) * rstd * gv.x + bv.x);
  o.y = f2bf((v.y - mean) * rstd * gv.y + bv.y);
  o.z = f2bf((v.z - mean) * rstd * gv.z + bv.z);
  o.w = f2bf((v.w - mean) * rstd * gv.w + bv.w);
  reinterpret_cast<ushort4*>(out + (size_t)row * 1024)[tid] = o;
}

// ---------- bf16 MFMA GEMM: C[M][N] = A[M][K] * Bt[N][K]^T ----------
// BK=64, DOUBLE-buffered with counted vmcnt + raw barriers (loads stay in flight
// across the compute phase). T2 swizzle both sides (chunk ^= row&7). TM x 128, 4 waves.
// MODE 0: f32 out + bias + resid; 1: bf16 relu + bias; 2: dual bf16 (C, C*KSCL);
// MODE 3: Vt transposed out, scaled by scvec (colrcp).
#define KSCL 0.04508422f  /* (1/32) * log2(e): S*KSCL feeds exp2 */

template<int TM, int MODE>
__global__ __launch_bounds__(256) void gemm_bf16(const unsigned short* __restrict__ A,
                                                 const unsigned short* __restrict__ Bt,
                                                 void* __restrict__ Cout,
                                                 unsigned short* __restrict__ Cout2,
                                                 const float* __restrict__ bias,
                                                 const float* __restrict__ resid,
                                                 const float* __restrict__ scvec,
                                                 int M, int N, int K) {
  constexpr int MI  = TM / 32;
  constexpr int ALD = TM / 32;       // A gl_lds per thread per tile
  constexpr int NLD = ALD + 4;       // total loads/thread/tile
  __shared__ __align__(16) unsigned short Sh[2][(TM + 128) * 64];
  int tid = threadIdx.x;
  int lane = tid & 63, w = tid >> 6;
  int l15 = lane & 15, lh = lane >> 4;
  int wr = (w >> 1) * (TM / 2), wc = (w & 1) * 64;
  int nblk = N >> 7;
  int rows = M / TM;
  int bm, bn;
  if ((rows & 7) == 0) {
    // XCD supertile: each XCD gets a contiguous (rows/8)-bm band x all bn
    int bid = blockIdx.x;
    int xcd = bid & 7, g = bid >> 3;
    bm = xcd * (rows >> 3) + g / nblk;
    bn = g % nblk;
  } else {
    bm = blockIdx.x / nblk; bn = blockIdx.x % nblk;
  }
  // per-thread staging sources (pre-swizzled global, linear LDS dest)
  const unsigned short* Asrc[ALD];
  const unsigned short* Bsrc[4];
#pragma unroll
  for (int j = 0; j < ALD; ++j) {
    int row = j * 32 + (tid >> 3);
    int ch  = (tid & 7) ^ (row & 7);
    Asrc[j] = A + (size_t)(bm * TM + row) * K + ch * 8;
  }
#pragma unroll
  for (int j = 0; j < 4; ++j) {
    int row = j * 32 + (tid >> 3);
    int ch  = (tid & 7) ^ (row & 7);
    Bsrc[j] = Bt + (size_t)(bn * 128 + row) * K + ch * 8;
  }
  f32x4 acc[MI][4] = {};
  int NT = K >> 6;
  // prologue: tile 0 -> buf 0
  {
#pragma unroll
    for (int j = 0; j < ALD; ++j) gl_lds16(Asrc[j], &Sh[0][(j * 256 + tid) * 8]);
#pragma unroll
    for (int j = 0; j < 4; ++j)  gl_lds16(Bsrc[j], &Sh[0][TM * 64 + (j * 256 + tid) * 8]);
  }
  for (int t = 0; t < NT; ++t) {
    int cur = t & 1;
    const unsigned short* Asc = &Sh[cur][0];
    const unsigned short* Bsc = &Sh[cur][TM * 64];
    if (t + 1 < NT) {
      int k0 = (t + 1) << 6;
      unsigned short* Asn = &Sh[cur ^ 1][0];
      unsigned short* Bsn = &Sh[cur ^ 1][TM * 64];
#pragma unroll
      for (int j = 0; j < ALD; ++j) gl_lds16(Asrc[j] + k0, Asn + (j * 256 + tid) * 8);
#pragma unroll
      for (int j = 0; j < 4; ++j)  gl_lds16(Bsrc[j] + k0, Bsn + (j * 256 + tid) * 8);
      asm volatile("s_waitcnt vmcnt(%0)" :: "i"(NLD) : "memory");  // tile t landed; t+1 in flight
    } else {
      asm volatile("s_waitcnt vmcnt(0)" ::: "memory");
    }
    __builtin_amdgcn_s_barrier();        // all waves' tile-t loads visible
    bf16x8 af[MI][2], bfr[4][2];
#pragma unroll
    for (int i = 0; i < MI; ++i)
#pragma unroll
      for (int kk = 0; kk < 2; ++kk)
        af[i][kk] = rdsw64(Asc, wr + i * 16 + l15, kk * 4 + lh);
#pragma unroll
    for (int i = 0; i < 4; ++i)
#pragma unroll
      for (int kk = 0; kk < 2; ++kk)
        bfr[i][kk] = rdsw64(Bsc, wc + i * 16 + l15, kk * 4 + lh);
    __builtin_amdgcn_s_setprio(1);
#pragma unroll
    for (int kk = 0; kk < 2; ++kk)
#pragma unroll
      for (int mi = 0; mi < MI; ++mi)
#pragma unroll
        for (int ni = 0; ni < 4; ++ni)
          acc[mi][ni] = mfma16(af[mi][kk], bfr[ni][kk], acc[mi][ni]);
    __builtin_amdgcn_s_setprio(0);
    __builtin_amdgcn_s_barrier();        // reads of buf cur done before it is restaged
  }
  unsigned short* Sh0 = &Sh[0][0];
  if constexpr (MODE == 3) {
#pragma unroll
    for (int mi = 0; mi < MI; ++mi) {
#pragma unroll
      for (int ni = 0; ni < 4; ++ni) {
        int tl = wr + mi * 16 + lh * 4;
        int dl = wc + ni * 16 + l15;
        int colg = bn * 128 + dl;
        int bb = bm >> 5, hh = colg >> 6;
        const float* sp = scvec + (size_t)(bb * 16 + hh) * 2048 + (bm & 31) * 64 + tl;
        float4 rs = *reinterpret_cast<const float4*>(sp);
        unsigned int p0 = f2bf(acc[mi][ni][0] * rs.x) | ((unsigned int)f2bf(acc[mi][ni][1] * rs.y) << 16);
        unsigned int p1 = f2bf(acc[mi][ni][2] * rs.z) | ((unsigned int)f2bf(acc[mi][ni][3] * rs.w) << 16);
        uint2 pk = {p0, p1};
        *reinterpret_cast<uint2*>(&Sh0[dl * 64 + (tl ^ ((dl & 7) << 3))]) = pk;
      }
    }
    __syncthreads();
    int dr = tid >> 1, th = (tid & 1) * 32;
    int bb = bm >> 5, tbase = (bm & 31) * 64;
    size_t colg = bn * 128 + dr;
    unsigned short* Vt = (unsigned short*)Cout;
#pragma unroll
    for (int j = 0; j < 4; ++j) {
      int t = th + j * 8;
      int4 v = *reinterpret_cast<const int4*>(&Sh0[dr * 64 + (t ^ ((dr & 7) << 3))]);
      *reinterpret_cast<int4*>(&Vt[((size_t)bb * 1024 + colg) * 2048 + tbase + t]) = v;
    }
  } else {
#pragma unroll
    for (int mi = 0; mi < MI; ++mi) {
#pragma unroll
      for (int ni = 0; ni < 4; ++ni) {
        int row0 = bm * TM + wr + mi * 16 + lh * 4;
        int col  = bn * 128 + wc + ni * 16 + l15;
        float bv = (MODE == 2) ? 0.f : bias[col];
#pragma unroll
        for (int r = 0; r < 4; ++r) {
          int row = row0 + r;
          float v = acc[mi][ni][r] + bv;
          if constexpr (MODE == 0) {
            v += resid[(size_t)row * N + col];
            ((float*)Cout)[(size_t)row * N + col] = v;
          } else if constexpr (MODE == 1) {
            v = fmaxf(v, 0.f);
            ((unsigned short*)Cout)[(size_t)row * N + col] = f2bf(v);
          } else {
            ((unsigned short*)Cout)[(size_t)row * N + col] = f2bf(v);
            Cout2[(size_t)row * N + col] = f2bf(v * KSCL);
          }
        }
      }
    }
  }
}

// ---------- attention pass A: l_s = sum_{t>=s} exp2(S[t,s]*KSCL); colrcp = 1/l ----------
// Grid 512, 8 waves x 16 s-rows (s-block 128). Long blocks (low sb) dispatch first (LPT).
__global__ __launch_bounds__(512) void attn_stats(const unsigned short* __restrict__ Kb,
                                                  const unsigned short* __restrict__ Kbs,
                                                  float* __restrict__ colrcp) {
  __shared__ __align__(16) unsigned short Kt[2][64 * 64];
  int bid = blockIdx.x;
  int q = bid >> 8, x = (bid >> 5) & 7, bh = bid & 31;
  int b = bh >> 4, h = bh & 15;
  int sb = q ? (15 - x) : x;   // q=0 -> sb 0..7 (longest first)
  int tid = threadIdx.x, lane = tid & 63, w = tid >> 6;
  int l15 = lane & 15, lh = lane >> 4;
  int s0 = sb * 128, sw = s0 + w * 16;
  const unsigned short* Kp  = Kb  + ((size_t)b * 2048) * 1024 + h * 64;
  const unsigned short* Kps = Kbs + ((size_t)b * 2048) * 1024 + h * 64;
  bf16x8 as[2];
#pragma unroll
  for (int kc = 0; kc < 2; ++kc)
    as[kc] = *reinterpret_cast<const bf16x8*>(Kp + (size_t)(sw + l15) * 1024 + kc * 32 + (lh << 3));
  int srow = tid >> 3;
  int sch  = (tid & 7) ^ (srow & 7);
  const unsigned short* ksrc = Kps + (size_t)srow * 1024 + sch * 8;
  gl_lds16(ksrc + (size_t)s0 * 1024, &Kt[0][tid * 8]);
  __syncthreads();
  float l[4] = {0.f, 0.f, 0.f, 0.f};
  int nt = 32 - 2 * sb;
  for (int it = 0; it < nt; ++it) {
    int t0 = s0 + it * 64;
    int cur = it & 1;
    if (it + 1 < nt)
      gl_lds16(ksrc + (size_t)(t0 + 64) * 1024, &Kt[cur ^ 1][tid * 8]);
    if (t0 + 63 >= sw) {               // tile not entirely below diagonal
      bool dmask = (t0 < sw + 16);
#pragma unroll
      for (int tf = 0; tf < 4; ++tf) {
        int tr = tf * 16 + l15;
        bf16x8 bt0 = rdsw64(&Kt[cur][0], tr, lh);
        bf16x8 bt1 = rdsw64(&Kt[cur][0], tr, 4 + lh);
        f32x4 z = {};
        f32x4 sa = mfma16(as[1], bt1, mfma16(as[0], bt0, z));  // D[s][t], lane col = t
        int tg = t0 + tr;
#pragma unroll
        for (int r = 0; r < 4; ++r) {
          float e = fexp2(sa[r]);
          if (dmask) { int sg = sw + lh * 4 + r; e = (tg >= sg) ? e : 0.f; }
          l[r] += e;
        }
      }
    }
    __syncthreads();   // drains gl_lds (vmcnt 0) + releases buffer cur
  }
#pragma unroll
  for (int m = 1; m < 16; m <<= 1)
#pragma unroll
    for (int r = 0; r < 4; ++r)
      l[r] += __shfl_xor(l[r], m);
  if (l15 == 0) {
#pragma unroll
    for (int r = 0; r < 4; ++r)
      colrcp[(size_t)bh * 2048 + sw + lh * 4 + r] = 1.f / l[r];
  }
}

// ---------- attention pass B: O[t,d] = sum_{s<=t} exp2(S*KSCL) * V'[s,d] ----------
// Grid 512, 8 waves x 16 t-rows (t-block 128). LPT: long blocks (high tb) first.
// T15 2-deep pipeline: PV(it-1) overlaps QK(it). Ks double, Vs triple, Pl double.
__global__ __launch_bounds__(512) void attn_pv(const unsigned short* __restrict__ Kb,
                                               const unsigned short* __restrict__ Kbs,
                                               const unsigned short* __restrict__ Vt,
                                               unsigned short* __restrict__ attn) {
  __shared__ __align__(16) unsigned short Ks[2][64 * 64];
  __shared__ __align__(16) unsigned short Vs[3][64 * 64];
  __shared__ __align__(16) unsigned short Pl[8][2][16][68];
  int bid = blockIdx.x;
  int q = bid >> 8, x = (bid >> 5) & 7, bh = bid & 31;
  int b = bh >> 4, h = bh & 15;
  int tb = q ? x : (15 - x);   // q=0 -> tb 15..8 (longest first: LPT)
  int tid = threadIdx.x, lane = tid & 63, w = tid >> 6;
  int l15 = lane & 15, lh = lane >> 4;
  int t0 = tb * 128, tw = t0 + w * 16;
  const unsigned short* Kp  = Kb  + ((size_t)b * 2048) * 1024 + h * 64;
  const unsigned short* Kps = Kbs + ((size_t)b * 2048) * 1024 + h * 64;
  const unsigned short* Vp  = Vt + (size_t)bh * 64 * 2048;
  bf16x8 at[2];
#pragma unroll
  for (int kc = 0; kc < 2; ++kc)
    at[kc] = *reinterpret_cast<const bf16x8*>(Kp + (size_t)(tw + l15) * 1024 + kc * 32 + (lh << 3));
  int srow = tid >> 3;
  int sch  = (tid & 7) ^ (srow & 7);
  const unsigned short* ksrc = Kps + (size_t)srow * 1024 + sch * 8;
  const unsigned short* vsrc = Vp + (size_t)srow * 2048 + sch * 8;
  int nt = 2 * tb + 2;
  gl_lds16(ksrc, &Ks[0][tid * 8]);
  gl_lds16(vsrc, &Vs[0][tid * 8]);
  __syncthreads();
  f32x4 acc[4] = {};
  for (int it = 0; it < nt; ++it) {
    int s0 = it * 64;
    const unsigned short* ksCur = &Ks[it & 1][0];
    if (it + 1 < nt) {
      gl_lds16(ksrc + (size_t)(s0 + 64) * 1024, &Ks[(it + 1) & 1][tid * 8]);
      gl_lds16(vsrc + (s0 + 64), &Vs[(it + 1) % 3][tid * 8]);
    }
    // QK(it): D[s][t] (A = Ks rows s, B = at rows t) -> Pl[w][it&1]
    if (s0 <= tw + 15) {
      bool dmask = (s0 + 63 > tw);
#pragma unroll
      for (int sf = 0; sf < 4; ++sf) {
        int sr = sf * 16 + l15;
        bf16x8 ks0 = rdsw64(ksCur, sr, lh);
        bf16x8 ks1 = rdsw64(ksCur, sr, 4 + lh);
        f32x4 z = {};
        f32x4 sa = mfma16(ks1, at[1], mfma16(ks0, at[0], z));  // D[s][t]
        float pe[4];
#pragma unroll
        for (int r = 0; r < 4; ++r) {
          float p = fexp2(sa[r]);
          if (dmask) {
            int sg = s0 + sf * 16 + lh * 4 + r;
            int tg = tw + l15;
            p = (sg <= tg) ? p : 0.f;
          }
          pe[r] = p;
        }
        unsigned int u0 = cvtpk_bf16(pe[0], pe[1]);
        unsigned int u1 = cvtpk_bf16(pe[2], pe[3]);
        unsigned long long pk = (unsigned long long)u0 | ((unsigned long long)u1 << 32);
        *reinterpret_cast<unsigned long long*>(&Pl[w][it & 1][l15][sf * 16 + lh * 4]) = pk;
      }
    }
    // PV(it-1): D[t][d] (A = Pl[w][prev] rows t, B = Vs[prev] rows d)
    if (it > 0) {
      int pit = it - 1;
      if (pit * 64 <= tw + 15) {
        const unsigned short* vsPrev = &Vs[pit % 3][0];
#pragma unroll
        for (int c2 = 0; c2 < 2; ++c2) {
          bf16x8 pa = *reinterpret_cast<const bf16x8*>(&Pl[w][pit & 1][l15][c2 * 32 + (lh << 3)]);
#pragma unroll
          for (int nf = 0; nf < 4; ++nf) {
            int dr = nf * 16 + l15;
            bf16x8 vb = rdsw64(vsPrev, dr, c2 * 4 + lh);
            acc[nf] = mfma16(pa, vb, acc[nf]);
          }
        }
      }
    }
    __syncthreads();   // drains gl_lds (vmcnt 0) + releases buffers
  }
  // epilogue: PV(nt-1) — buffers stable after final barrier
  {
    int pit = nt - 1;
    if (pit * 64 <= tw + 15) {
      const unsigned short* vsPrev = &Vs[pit % 3][0];
#pragma unroll
      for (int c2 = 0; c2 < 2; ++c2) {
        bf16x8 pa = *reinterpret_cast<const bf16x8*>(&Pl[w][pit & 1][l15][c2 * 32 + (lh << 3)]);
#pragma unroll
        for (int nf = 0; nf < 4; ++nf) {
          int dr = nf * 16 + l15;
          bf16x8 vb = rdsw64(vsPrev, dr, c2 * 4 + lh);
          acc[nf] = mfma16(pa, vb, acc[nf]);
        }
      }
    }
  }
#pragma unroll
  for (int nf = 0; nf < 4; ++nf)
#pragma unroll
    for (int r = 0; r < 4; ++r) {
      int t = tw + lh * 4 + r;
      attn[(size_t)(b * 2048 + t) * 1024 + h * 64 + nf * 16 + l15] = f2bf(acc[nf][r]);
    }
}

extern "C" void kernel_launch(void* const* d_in, const int* in_sizes, int n_in,
                              void* d_out, int out_size, void* d_ws, size_t ws_size,
                              hipStream_t stream) {
  (void)in_sizes; (void)n_in; (void)out_size; (void)ws_size;
  const float* x     = (const float*)d_in[0];
  const float* ln1_g = (const float*)d_in[1];
  const float* ln1_b = (const float*)d_in[2];
  const float* Wk    = (const float*)d_in[3];
  const float* Wv    = (const float*)d_in[4];
  const float* Wproj = (const float*)d_in[5];
  const float* bproj = (const float*)d_in[6];
  const float* ln2_g = (const float*)d_in[7];
  const float* ln2_b = (const float*)d_in[8];
  const float* W1    = (const float*)d_in[9];
  const float* b1    = (const float*)d_in[10];
  const float* W2    = (const float*)d_in[11];
  const float* b2    = (const float*)d_in[12];
  float* out = (float*)d_out;

  char* ws = (char*)d_ws;
  size_t off = 0;
  auto alloc = [&](size_t bytes) { void* p = ws + off; off += (bytes + 255) & ~(size_t)255; return p; };
  unsigned short* bufA = (unsigned short*)alloc((size_t)4096 * 1024 * 2);  // h1 -> attn -> h2
  unsigned short* wk_t = (unsigned short*)alloc((size_t)1024 * 1024 * 2);
  unsigned short* wv_t = (unsigned short*)alloc((size_t)1024 * 1024 * 2);
  unsigned short* wp_t = (unsigned short*)alloc((size_t)1024 * 1024 * 2);
  unsigned short* w1_t = (unsigned short*)alloc((size_t)1024 * 4096 * 2);
  unsigned short* w2_t = (unsigned short*)alloc((size_t)4096 * 1024 * 2);
  unsigned short* Kb   = (unsigned short*)alloc((size_t)4096 * 1024 * 2);
  unsigned short* Kbs  = (unsigned short*)alloc((size_t)4096 * 1024 * 2);
  unsigned short* Vt   = (unsigned short*)alloc((size_t)4096 * 1024 * 2);
  float* colrcp = (float*)alloc((size_t)32 * 2048 * 4);
  float* y      = (float*)alloc((size_t)4096 * 1024 * 4);
  unsigned short* act = (unsigned short*)alloc((size_t)4096 * 4096 * 2);

  dim3 b256(256), b512(512);
  transpose_cvt<<<dim3(2, 32, 16), b256, 0, stream>>>(Wk, wk_t, 1024, 64);
  transpose_cvt<<<dim3(2, 32, 16), b256, 0, stream>>>(Wv, wv_t, 1024, 64);
  transpose_cvt<<<dim3(32, 32, 1), b256, 0, stream>>>(Wproj, wp_t, 1024, 1024);
  transpose_cvt<<<dim3(128, 32, 1), b256, 0, stream>>>(W1, w1_t, 1024, 4096);
  transpose_cvt<<<dim3(32, 128, 1), b256, 0, stream>>>(W2, w2_t, 4096, 1024);

  // LN1
  ln_bf16<<<4096, b256, 0, stream>>>(x, ln1_g, ln1_b, bufA);
  // K (and K*KSCL) = h @ Wk
  gemm_bf16<64, 2><<<512, b256, 0, stream>>>(bufA, wk_t, Kb, Kbs, nullptr, nullptr, nullptr, 4096, 1024, 1024);
  // column softmax denominators
  attn_stats<<<512, b512, 0, stream>>>(Kb, Kbs, colrcp);
  // V' = (h @ Wv) * colrcp, stored transposed [b,h,d,t]
  gemm_bf16<64, 3><<<512, b256, 0, stream>>>(bufA, wv_t, Vt, nullptr, nullptr, nullptr, colrcp, 4096, 1024, 1024);
  // O = exp2(S*KSCL) @ V'
  attn_pv<<<512, b512, 0, stream>>>(Kb, Kbs, Vt, bufA);
  // y = x + O @ Wproj + bproj
  gemm_bf16<64, 0><<<512, b256, 0, stream>>>(bufA, wp_t, y, nullptr, bproj, x, nullptr, 4096, 1024, 1024);
  // LN2
  ln_bf16<<<4096, b256, 0, stream>>>(y, ln2_g, ln2_b, bufA);
  // act = relu(h2 @ W1 + b1)  -- 128x128 counted-vmcnt kernel, 1024 blocks (2/CU)
  gemm_bf16<128, 1><<<1024, b256, 0, stream>>>(bufA, w1_t, act, nullptr, b1, nullptr, nullptr, 4096, 4096, 1024);
  // out = y + act @ W2 + b2
  gemm_bf16<64, 0><<<512, b256, 0, stream>>>(act, w2_t, out, nullptr, b2, y, nullptr, 4096, 1024, 4096);
}